// Round 14
// baseline (53.345 us; speedup 1.0000x reference)
//
#include <hip/hip_runtime.h>

// B=256, T=256, D=384, HD=64
typedef __attribute__((ext_vector_type(8))) short bf16x8;
typedef __attribute__((ext_vector_type(4))) float f32x4;

__device__ inline unsigned short f2bf(float f) {
    unsigned u = __float_as_uint(f);
    return (unsigned short)((u + 0x7fffu + ((u >> 16) & 1u)) >> 16);
}

// ---------------------------------------------------------------------------
// Kernel 0 (R7/R9-verified): W = [Wq;Wk;Wv] -> bf16 frag-major pre-swizzled:
//   Wp[kc*6144 + (((g*192 + col) ^ g) << 3) + kl] = W[col][kc*32 + g*8 + kl]
// ---------------------------------------------------------------------------
__global__ void wconv(const float* __restrict__ Wq, const float* __restrict__ Wk,
                      const float* __restrict__ Wv, short* __restrict__ Wp) {
    int i = blockIdx.x * 256 + threadIdx.x;
    if (i >= 192 * 384) return;
    int col = i / 384;
    int k   = i - col * 384;
    const float* src = col < 64 ? (Wq + col * 384)
                     : col < 128 ? (Wk + (col - 64) * 384)
                                 : (Wv + (col - 128) * 384);
    int kc = k >> 5, g = (k >> 3) & 3, kl = k & 7;
    Wp[kc * 6144 + (((g * 192 + col) ^ g) << 3) + kl] = (short)f2bf(src[k]);
}

// ---------------------------------------------------------------------------
// Fused kernel v5 = R13 with phase-1 made BARRIER-FREE.
// Diagnosis R7-R13: every per-pipe cost sums to <<measured; phase-1 was a
// per-step serial latency chain (barrier -> vmcnt(L3-latency x) -> lgkm ->
// MFMA) convoyed across 16 waves by the per-step s_barrier.  Fix: eliminate
// the only reason for in-loop barriers (W LDS staging).  B-frags read
// DIRECTLY from global Wp: all 16 waves read the same 12KB/step -> wave 1
// fills L1, others hit L1 (broadcast at LDS-class BW, no sync).  x stays
// direct-to-reg triple-set 2 ahead (R13).  Phase-1 now has ZERO LDS ops,
// ZERO barriers, ZERO asm waits -- 16 waves free-run, compiler pipelines.
// Epilogue (acc -> Ksh/Vt, Q via per-wave Pb) + phase 2: R13-verbatim.
// ---------------------------------------------------------------------------
__global__ __launch_bounds__(1024) void fused_attn(
    const float* __restrict__ x, const short* __restrict__ Wp,
    float* __restrict__ out) {
    __shared__ short LDSH[45568];          // 91136 B
    short* const Ksh = LDSH;               // [256*72]
    short* const Vt  = LDSH + 18432;       // [64*264]
    short* const Pb  = LDSH + 35328;       // [16*640]

    const int tid = threadIdx.x;
    const int wv = tid >> 6, lane = tid & 63;
    const int g = lane >> 4, c = lane & 15;
    const int b = blockIdx.x;
    const int q0 = wv * 16;

    // direct x addressing: lane (g,c) of wave wv reads row q0+c, cols s*32+g*8
    const float* gxw = x + ((size_t)b * 256 + q0 + c) * 384 + g * 8;

    f32x4 acc[12];
#pragma unroll
    for (int j = 0; j < 12; ++j) acc[j] = (f32x4){0.f, 0.f, 0.f, 0.f};

#define COMPUTE(S, F0, F1)                                                    \
    {                                                                         \
        const short* wp_ = Wp + (S) * 6144;                                   \
        bf16x8 af;                                                            \
        af[0] = (short)f2bf((F0).x); af[1] = (short)f2bf((F0).y);             \
        af[2] = (short)f2bf((F0).z); af[3] = (short)f2bf((F0).w);             \
        af[4] = (short)f2bf((F1).x); af[5] = (short)f2bf((F1).y);             \
        af[6] = (short)f2bf((F1).z); af[7] = (short)f2bf((F1).w);             \
        _Pragma("unroll")                                                     \
        for (int h_ = 0; h_ < 2; ++h_) {                                      \
            bf16x8 bfr[6];                                                    \
            _Pragma("unroll")                                                 \
            for (int j6 = 0; j6 < 6; ++j6) {                                  \
                int col = (h_ * 6 + j6) * 16 + c;                             \
                bfr[j6] = *(const bf16x8*)&wp_[((g * 192 + col) ^ g) << 3];   \
            }                                                                 \
            _Pragma("unroll")                                                 \
            for (int j6 = 0; j6 < 6; ++j6)                                    \
                acc[h_ * 6 + j6] = __builtin_amdgcn_mfma_f32_16x16x32_bf16(   \
                    af, bfr[j6], acc[h_ * 6 + j6], 0, 0, 0);                  \
        }                                                                     \
    }
// STEP(S): issue x(S+2) into LD set; compute S from CUR set.  No barriers,
// no waits -- data-flow only; compiler pipelines across steps freely.
#define STEP(S, LD0, LD1, CUR0, CUR1)                                        \
    {                                                                        \
        if ((S) <= 9) {                                                      \
            LD0 = *(const float4*)(gxw + ((S) + 2) * 32);                    \
            LD1 = *(const float4*)(gxw + ((S) + 2) * 32 + 4);                 \
        }                                                                    \
        COMPUTE(S, CUR0, CUR1)                                               \
    }

    float4 xA0, xA1, xB0, xB1, xC0, xC1;

    // prologue: x0 -> A, x1 -> B (compiler inserts the waits it needs)
    xA0 = *(const float4*)(gxw);
    xA1 = *(const float4*)(gxw + 4);
    xB0 = *(const float4*)(gxw + 32);
    xB1 = *(const float4*)(gxw + 36);

    // 12 steps; x(k) lives in set k%3 (A,B,C), all indices static
    STEP(0,  xC0, xC1, xA0, xA1)
    STEP(1,  xA0, xA1, xB0, xB1)
    STEP(2,  xB0, xB1, xC0, xC1)
    STEP(3,  xC0, xC1, xA0, xA1)
    STEP(4,  xA0, xA1, xB0, xB1)
    STEP(5,  xB0, xB1, xC0, xC1)
    STEP(6,  xC0, xC1, xA0, xA1)
    STEP(7,  xA0, xA1, xB0, xB1)
    STEP(8,  xB0, xB1, xC0, xC1)
    STEP(9,  xC0, xC1, xA0, xA1)
    STEP(10, xA0, xA1, xB0, xB1)
    COMPUTE(11, xC0, xC1)
    __syncthreads();

    // ---- epilogue (R13-verbatim): acc -> K/V LDS; Q -> regs via Pb.
    // C/D layout (verified): within 16x16 tile, col = c, row = 4g + r.
    short* const pbw = Pb + wv * 640;
    bf16x8 qf0, qf1;
    {
#pragma unroll
        for (int r = 0; r < 4; ++r) {
            pbw[(4 * g + r) * 40 + c]      = (short)f2bf(acc[0][r]);
            pbw[(4 * g + r) * 40 + 16 + c] = (short)f2bf(acc[1][r]);
        }
        qf0 = *(const bf16x8*)&pbw[c * 40 + g * 8];
#pragma unroll
        for (int r = 0; r < 4; ++r) {
            pbw[(4 * g + r) * 40 + c]      = (short)f2bf(acc[2][r]);
            pbw[(4 * g + r) * 40 + 16 + c] = (short)f2bf(acc[3][r]);
        }
        qf1 = *(const bf16x8*)&pbw[c * 40 + g * 8];
    }
#pragma unroll
    for (int nj = 4; nj < 8; ++nj) {
        const int row = q0 + 4 * g;
#pragma unroll
        for (int r = 0; r < 4; ++r)
            Ksh[(row + r) * 72 + (nj - 4) * 16 + c] = (short)f2bf(acc[nj][r]);
    }
#pragma unroll
    for (int nj = 8; nj < 12; ++nj) {
        const int h = (nj - 8) * 16 + c;
        const int swz = ((h >> 3) & 7) << 3;
        const int row = q0 + 4 * g;
#pragma unroll
        for (int r = 0; r < 4; ++r)
            Vt[(h * 264 + row + r) ^ swz] = (short)f2bf(acc[nj][r]);
    }
    __syncthreads();

    // ---------------- Phase 2: causal attention (R13-verbatim) --------------
    {
        f32x4 o[4];
#pragma unroll
        for (int nj = 0; nj < 4; ++nj) o[nj] = (f32x4){0.f, 0.f, 0.f, 0.f};
        float m[4] = {-INFINITY, -INFINITY, -INFINITY, -INFINITY};
        float ls[4] = {0.f, 0.f, 0.f, 0.f};
        const int jmax = (q0 + 15) >> 5;

        for (int j = 0; j <= jmax; ++j) {
            f32x4 s0 = {0.f, 0.f, 0.f, 0.f}, s1 = {0.f, 0.f, 0.f, 0.f};
            {
                bf16x8 kf;
                kf = *(const bf16x8*)&Ksh[(32 * j + c) * 72 + g * 8];
                s0 = __builtin_amdgcn_mfma_f32_16x16x32_bf16(qf0, kf, s0, 0, 0, 0);
                kf = *(const bf16x8*)&Ksh[(32 * j + c) * 72 + 32 + g * 8];
                s0 = __builtin_amdgcn_mfma_f32_16x16x32_bf16(qf1, kf, s0, 0, 0, 0);
                kf = *(const bf16x8*)&Ksh[(32 * j + 16 + c) * 72 + g * 8];
                s1 = __builtin_amdgcn_mfma_f32_16x16x32_bf16(qf0, kf, s1, 0, 0, 0);
                kf = *(const bf16x8*)&Ksh[(32 * j + 16 + c) * 72 + 32 + g * 8];
                s1 = __builtin_amdgcn_mfma_f32_16x16x32_bf16(qf1, kf, s1, 0, 0, 0);
            }
            float t0[4], t1[4];
#pragma unroll
            for (int r = 0; r < 4; ++r) {
                t0[r] = s0[r] * 0.125f;
                t1[r] = s1[r] * 0.125f;
            }
            if (j == jmax) {   // wave-uniform: diagonal tile, causal mask
                int q = q0 + 4 * g;
#pragma unroll
                for (int r = 0; r < 4; ++r) {
                    if (32 * j + c > q + r) t0[r] = -INFINITY;
                    if (32 * j + 16 + c > q + r) t1[r] = -INFINITY;
                }
            }
            float corr[4], p0[4], p1[4];
#pragma unroll
            for (int r = 0; r < 4; ++r) {
                float v = fmaxf(t0[r], t1[r]);
#pragma unroll
                for (int off = 1; off < 16; off <<= 1) v = fmaxf(v, __shfl_xor(v, off, 16));
                float mn = fmaxf(m[r], v);
                corr[r] = __expf(m[r] - mn);   // first tile: exp(-inf)=0
                m[r] = mn;
                p0[r] = __expf(t0[r] - mn);
                p1[r] = __expf(t1[r] - mn);
                float rs = p0[r] + p1[r];
#pragma unroll
                for (int off = 1; off < 16; off <<= 1) rs += __shfl_xor(rs, off, 16);
                ls[r] = ls[r] * corr[r] + rs;
            }
#pragma unroll
            for (int nj = 0; nj < 4; ++nj) {
                f32x4 t = o[nj];
                t[0] *= corr[0]; t[1] *= corr[1]; t[2] *= corr[2]; t[3] *= corr[3];
                o[nj] = t;
            }
            // P -> Pb (C/D rows) -> A-frag read (same-wave RAW, in-order LDS)
#pragma unroll
            for (int r = 0; r < 4; ++r) {
                pbw[(4 * g + r) * 40 + c]      = (short)f2bf(p0[r]);
                pbw[(4 * g + r) * 40 + 16 + c] = (short)f2bf(p1[r]);
            }
            bf16x8 pfa = *(const bf16x8*)&pbw[c * 40 + g * 8];
#pragma unroll
            for (int nj = 0; nj < 4; ++nj) {
                int h = 16 * nj + c;
                int swz = ((2 * nj + (c >> 3)) & 7) << 3;
                bf16x8 vf = *(const bf16x8*)&Vt[(h * 264 + 32 * j + g * 8) ^ swz];
                o[nj] = __builtin_amdgcn_mfma_f32_16x16x32_bf16(pfa, vf, o[nj], 0, 0, 0);
            }
        }
        float inv[4];
#pragma unroll
        for (int r = 0; r < 4; ++r) inv[r] = 1.f / ls[r];
        float* ob = out + ((size_t)b * 256 + q0) * 64;
#pragma unroll
        for (int nj = 0; nj < 4; ++nj)
#pragma unroll
            for (int r = 0; r < 4; ++r)
                ob[(4 * g + r) * 64 + 16 * nj + c] = o[nj][r] * inv[r];
    }
#undef COMPUTE
#undef STEP
}

// ---------------------------------------------------------------------------
extern "C" void kernel_launch(void* const* d_in, const int* in_sizes, int n_in,
                              void* d_out, int out_size, void* d_ws, size_t ws_size,
                              hipStream_t stream) {
    const float* x  = (const float*)d_in[0];
    const float* Wq = (const float*)d_in[1];
    const float* Wk = (const float*)d_in[2];
    const float* Wv = (const float*)d_in[3];
    float* out = (float*)d_out;

    short* Wp = (short*)d_ws;   // 73728 shorts (144 KB)

    wconv<<<dim3(288), dim3(256), 0, stream>>>(Wq, Wk, Wv, Wp);
    fused_attn<<<dim3(256), dim3(1024), 0, stream>>>(x, Wp, out);
}

// Round 15
// 41.722 us; speedup vs baseline: 1.2786x; 1.2786x over previous
//
#include <hip/hip_runtime.h>

// B=256, T=256, D=384, HD=64
typedef __attribute__((ext_vector_type(8))) short bf16x8;
typedef __attribute__((ext_vector_type(4))) float f32x4;

__device__ inline unsigned short f2bf(float f) {
    unsigned u = __float_as_uint(f);
    return (unsigned short)((u + 0x7fffu + ((u >> 16) & 1u)) >> 16);
}
__device__ inline void gload16(const void* g, void* l) {
    __builtin_amdgcn_global_load_lds(
        (const __attribute__((address_space(1))) unsigned*)g,
        (__attribute__((address_space(3))) unsigned*)l, 16, 0, 0);
}

// ---------------------------------------------------------------------------
// Kernel 0 (R7/R9-verified): W = [Wq;Wk;Wv] -> bf16 frag-major pre-swizzled:
//   Wp[kc*6144 + (((g*192 + col) ^ g) << 3) + kl] = W[col][kc*32 + g*8 + kl]
// ---------------------------------------------------------------------------
__global__ void wconv(const float* __restrict__ Wq, const float* __restrict__ Wk,
                      const float* __restrict__ Wv, short* __restrict__ Wp) {
    int i = blockIdx.x * 256 + threadIdx.x;
    if (i >= 192 * 384) return;
    int col = i / 384;
    int k   = i - col * 384;
    const float* src = col < 64 ? (Wq + col * 384)
                     : col < 128 ? (Wk + (col - 64) * 384)
                                 : (Wv + (col - 128) * 384);
    int kc = k >> 5, g = (k >> 3) & 3, kl = k & 7;
    Wp[kc * 6144 + (((g * 192 + col) ^ g) << 3) + kl] = (short)f2bf(src[k]);
}

// ---------------------------------------------------------------------------
// Fused kernel v6 = R12 (41.1 best) with phase-1 wave grid 4Mx4N.
// R12's 16-wave/16-rows-each geometry made every wave read the ENTIRE 12KB
// W tile from LDS each step (16x replication, ~200KB LDS reads/step ~2.5Kcyc
// -> ~12us serialized over the barrier-locked k-loop).  4Mx4N (wave = 64
// rows x 48 cols) cuts per-step frag reads 13->7 per wave (W replication
// 16x->4x, x 1x->4x): 112KB/step total.  acc stays 4x3x f32x4 = 48 VGPR.
// Cost: waves no longer own their phase-2 q-rows -> Q routed through a
// dedicated Qlds [256][72] (R5/R7-verified pattern).  LDS 125KB, 1 block/CU.
// Schedule (counted vmcnt(2), raw barriers), W gload_lds dbuf, x XWRITE
// staging, epilogue layouts, phase-2: R12-verbatim.
// ---------------------------------------------------------------------------
__global__ __launch_bounds__(1024) void fused_attn(
    const float* __restrict__ x, const short* __restrict__ Wp,
    float* __restrict__ out) {
    __shared__ short LDSH[64000];           // 128000 B
    short* const Qlds = LDSH;               // [256*72]
    short* const Ksh  = LDSH + 18432;       // [256*72]
    short* const Vt   = LDSH + 36864;       // [64*264]
    short* const Pb   = LDSH + 53760;       // [16*640]
    short* const wst  = LDSH;               // W dbuf overlay (in Qlds region)
    short* const xst  = LDSH + 18432;       // x dbuf overlay (in Ksh+Vt region)

    const int tid = threadIdx.x;
    const int wv = tid >> 6, lane = tid & 63;
    const int g = lane >> 4, c = lane & 15;
    const int b = blockIdx.x;
    const int q0 = wv * 16;                 // phase-2 q-tile
    const int wm2 = (wv >> 2) * 64;         // phase-1 rows
    const int wn2 = (wv & 3) * 48;          // phase-1 cols

    // x staging map (R12-verbatim): thread -> rows xr0, xr0+128, chunk xc4
    const int xr0 = tid >> 3;               // 0..127
    const int xc4 = tid & 7;
    const float* gx0 = x + ((size_t)b * 256 + xr0) * 384 + xc4 * 4;
    const float* gx1 = gx0 + (size_t)128 * 384;

    f32x4 acc[4][3];
#pragma unroll
    for (int i = 0; i < 4; ++i)
#pragma unroll
        for (int j = 0; j < 3; ++j) acc[i][j] = (f32x4){0.f, 0.f, 0.f, 0.f};

#define STAGE_W(S, BUF)                                                       \
    if (wv < 12) gload16(Wp + (S) * 6144 + wv * 512 + lane * 8,               \
                         wst + (BUF) * 6144 + wv * 512);
#define XWRITE(BUF, A, Bv)                                                    \
    {                                                                         \
        uint2 p0_, p1_;                                                       \
        p0_.x = (unsigned)f2bf((A).x) | ((unsigned)f2bf((A).y) << 16);        \
        p0_.y = (unsigned)f2bf((A).z) | ((unsigned)f2bf((A).w) << 16);        \
        p1_.x = (unsigned)f2bf((Bv).x) | ((unsigned)f2bf((Bv).y) << 16);      \
        p1_.y = (unsigned)f2bf((Bv).z) | ((unsigned)f2bf((Bv).w) << 16);      \
        *(uint2*)&xst[(BUF) * 10240 + xr0 * 40 + xc4 * 4] = p0_;              \
        *(uint2*)&xst[(BUF) * 10240 + (xr0 + 128) * 40 + xc4 * 4] = p1_;      \
    }
#define COMPUTE(S)                                                            \
    {                                                                         \
        const short* xb = xst + ((S) & 1) * 10240;                            \
        const short* wb = wst + ((S) & 1) * 6144;                             \
        bf16x8 af[4], bfr[3];                                                 \
        _Pragma("unroll")                                                     \
        for (int mi = 0; mi < 4; ++mi)                                        \
            af[mi] = *(const bf16x8*)&xb[(wm2 + 16 * mi + c) * 40 + g * 8];   \
        _Pragma("unroll")                                                     \
        for (int nj = 0; nj < 3; ++nj) {                                      \
            int col = wn2 + nj * 16 + c;                                      \
            bfr[nj] = *(const bf16x8*)&wb[((g * 192 + col) ^ g) << 3];        \
        }                                                                     \
        _Pragma("unroll")                                                     \
        for (int mi = 0; mi < 4; ++mi)                                        \
            _Pragma("unroll")                                                 \
            for (int nj = 0; nj < 3; ++nj)                                    \
                acc[mi][nj] = __builtin_amdgcn_mfma_f32_16x16x32_bf16(        \
                    af[mi], bfr[nj], acc[mi][nj], 0, 0, 0);                   \
    }
// STEP(S): issue W(S+1); issue x(S+2) into LD regs; compute S; write x(S+1)
//          regs->LDS; counted vmcnt (W(S+1)+x(S+1) drained, x(S+2) stays);
//          raw barrier.
#define STEP(S, LD0, LD1, WX0, WX1)                                          \
    {                                                                        \
        STAGE_W((S) + 1, ((S) + 1) & 1)                                      \
        __builtin_amdgcn_sched_barrier(0);                                   \
        if ((S) <= 9) {                                                      \
            LD0 = *(const float4*)(gx0 + ((S) + 2) * 32);                    \
            LD1 = *(const float4*)(gx1 + ((S) + 2) * 32);                    \
        }                                                                    \
        __builtin_amdgcn_sched_barrier(0);                                   \
        COMPUTE(S)                                                           \
        XWRITE(((S) + 1) & 1, WX0, WX1)                                      \
        if (wv < 12) {                                                       \
            if ((S) <= 9) asm volatile("s_waitcnt vmcnt(2)" ::: "memory");   \
            else          asm volatile("s_waitcnt vmcnt(0)" ::: "memory");   \
        }                                                                    \
        asm volatile("s_waitcnt lgkmcnt(0)" ::: "memory");                   \
        __builtin_amdgcn_s_barrier();                                        \
        __builtin_amdgcn_sched_barrier(0);                                   \
    }

    float4 xA0, xA1, xB0, xB1, xC0, xC1;

    // prologue (R12-verbatim): x0 -> A, W0, x1 -> B; write x0; x1 in flight
    xA0 = *(const float4*)(gx0);
    xA1 = *(const float4*)(gx1);
    __builtin_amdgcn_sched_barrier(0);
    STAGE_W(0, 0)
    __builtin_amdgcn_sched_barrier(0);
    xB0 = *(const float4*)(gx0 + 32);
    xB1 = *(const float4*)(gx1 + 32);
    __builtin_amdgcn_sched_barrier(0);
    XWRITE(0, xA0, xA1)
    if (wv < 12) asm volatile("s_waitcnt vmcnt(2)" ::: "memory");
    asm volatile("s_waitcnt lgkmcnt(0)" ::: "memory");
    __builtin_amdgcn_s_barrier();
    __builtin_amdgcn_sched_barrier(0);

    // 12 steps; x(k) lives in set k%3 (A,B,C), all static
    STEP(0, xC0, xC1, xB0, xB1)
    STEP(1, xA0, xA1, xC0, xC1)
    STEP(2, xB0, xB1, xA0, xA1)
    STEP(3, xC0, xC1, xB0, xB1)
    STEP(4, xA0, xA1, xC0, xC1)
    STEP(5, xB0, xB1, xA0, xA1)
    STEP(6, xC0, xC1, xB0, xB1)
    STEP(7, xA0, xA1, xC0, xC1)
    STEP(8, xB0, xB1, xA0, xA1)
    STEP(9, xC0, xC1, xB0, xB1)
    STEP(10, xA0, xA1, xC0, xC1)           // no load (S>9); writes x11=C
    COMPUTE(11)
    __syncthreads();                        // all staging reads done

    // ---- epilogue: acc -> Qlds/Ksh/Vt (verified layouts).
    // C/D layout: within 16x16 tile, col = c, row = 4g + r.
#pragma unroll
    for (int mi = 0; mi < 4; ++mi) {
#pragma unroll
        for (int nj = 0; nj < 3; ++nj) {
            const int colb = wn2 + nj * 16;         // wave-uniform, 16-aligned
            const int row = wm2 + 16 * mi + 4 * g;
            if (colb < 64) {
#pragma unroll
                for (int r = 0; r < 4; ++r)
                    Qlds[(row + r) * 72 + colb + c] = (short)f2bf(acc[mi][nj][r]);
            } else if (colb < 128) {
#pragma unroll
                for (int r = 0; r < 4; ++r)
                    Ksh[(row + r) * 72 + (colb - 64) + c] = (short)f2bf(acc[mi][nj][r]);
            } else {
                const int h = colb - 128 + c;
                const int swz = ((h >> 3) & 7) << 3;
#pragma unroll
                for (int r = 0; r < 4; ++r)
                    Vt[(h * 264 + row + r) ^ swz] = (short)f2bf(acc[mi][nj][r]);
            }
        }
    }
    __syncthreads();

    // ---------------- Phase 2: causal attention (R12-verbatim, Q from Qlds) --
    {
        short* const pbw = Pb + wv * 640;
        bf16x8 qf0 = *(const bf16x8*)&Qlds[(q0 + c) * 72 + g * 8];
        bf16x8 qf1 = *(const bf16x8*)&Qlds[(q0 + c) * 72 + 32 + g * 8];
        f32x4 o[4];
#pragma unroll
        for (int nj = 0; nj < 4; ++nj) o[nj] = (f32x4){0.f, 0.f, 0.f, 0.f};
        float m[4] = {-INFINITY, -INFINITY, -INFINITY, -INFINITY};
        float ls[4] = {0.f, 0.f, 0.f, 0.f};
        const int jmax = (q0 + 15) >> 5;

        for (int j = 0; j <= jmax; ++j) {
            f32x4 s0 = {0.f, 0.f, 0.f, 0.f}, s1 = {0.f, 0.f, 0.f, 0.f};
            {
                bf16x8 kf;
                kf = *(const bf16x8*)&Ksh[(32 * j + c) * 72 + g * 8];
                s0 = __builtin_amdgcn_mfma_f32_16x16x32_bf16(qf0, kf, s0, 0, 0, 0);
                kf = *(const bf16x8*)&Ksh[(32 * j + c) * 72 + 32 + g * 8];
                s0 = __builtin_amdgcn_mfma_f32_16x16x32_bf16(qf1, kf, s0, 0, 0, 0);
                kf = *(const bf16x8*)&Ksh[(32 * j + 16 + c) * 72 + g * 8];
                s1 = __builtin_amdgcn_mfma_f32_16x16x32_bf16(qf0, kf, s1, 0, 0, 0);
                kf = *(const bf16x8*)&Ksh[(32 * j + 16 + c) * 72 + 32 + g * 8];
                s1 = __builtin_amdgcn_mfma_f32_16x16x32_bf16(qf1, kf, s1, 0, 0, 0);
            }
            float t0[4], t1[4];
#pragma unroll
            for (int r = 0; r < 4; ++r) {
                t0[r] = s0[r] * 0.125f;
                t1[r] = s1[r] * 0.125f;
            }
            if (j == jmax) {   // wave-uniform: diagonal tile, causal mask
                int q = q0 + 4 * g;
#pragma unroll
                for (int r = 0; r < 4; ++r) {
                    if (32 * j + c > q + r) t0[r] = -INFINITY;
                    if (32 * j + 16 + c > q + r) t1[r] = -INFINITY;
                }
            }
            float corr[4], p0[4], p1[4];
#pragma unroll
            for (int r = 0; r < 4; ++r) {
                float v = fmaxf(t0[r], t1[r]);
#pragma unroll
                for (int off = 1; off < 16; off <<= 1) v = fmaxf(v, __shfl_xor(v, off, 16));
                float mn = fmaxf(m[r], v);
                corr[r] = __expf(m[r] - mn);   // first tile: exp(-inf)=0
                m[r] = mn;
                p0[r] = __expf(t0[r] - mn);
                p1[r] = __expf(t1[r] - mn);
                float rs = p0[r] + p1[r];
#pragma unroll
                for (int off = 1; off < 16; off <<= 1) rs += __shfl_xor(rs, off, 16);
                ls[r] = ls[r] * corr[r] + rs;
            }
#pragma unroll
            for (int nj = 0; nj < 4; ++nj) {
                f32x4 t = o[nj];
                t[0] *= corr[0]; t[1] *= corr[1]; t[2] *= corr[2]; t[3] *= corr[3];
                o[nj] = t;
            }
            // P -> Pb (C/D rows) -> A-frag read (same-wave RAW, in-order LDS)
#pragma unroll
            for (int r = 0; r < 4; ++r) {
                pbw[(4 * g + r) * 40 + c]      = (short)f2bf(p0[r]);
                pbw[(4 * g + r) * 40 + 16 + c] = (short)f2bf(p1[r]);
            }
            bf16x8 pfa = *(const bf16x8*)&pbw[c * 40 + g * 8];
#pragma unroll
            for (int nj = 0; nj < 4; ++nj) {
                int h = 16 * nj + c;
                int swz = ((2 * nj + (c >> 3)) & 7) << 3;
                bf16x8 vf = *(const bf16x8*)&Vt[(h * 264 + 32 * j + g * 8) ^ swz];
                o[nj] = __builtin_amdgcn_mfma_f32_16x16x32_bf16(pfa, vf, o[nj], 0, 0, 0);
            }
        }
        float inv[4];
#pragma unroll
        for (int r = 0; r < 4; ++r) inv[r] = 1.f / ls[r];
        float* ob = out + ((size_t)b * 256 + q0) * 64;
#pragma unroll
        for (int nj = 0; nj < 4; ++nj)
#pragma unroll
            for (int r = 0; r < 4; ++r)
                ob[(4 * g + r) * 64 + 16 * nj + c] = o[nj][r] * inv[r];
    }
#undef STAGE_W
#undef XWRITE
#undef COMPUTE
#undef STEP
}

// ---------------------------------------------------------------------------
extern "C" void kernel_launch(void* const* d_in, const int* in_sizes, int n_in,
                              void* d_out, int out_size, void* d_ws, size_t ws_size,
                              hipStream_t stream) {
    const float* x  = (const float*)d_in[0];
    const float* Wq = (const float*)d_in[1];
    const float* Wk = (const float*)d_in[2];
    const float* Wv = (const float*)d_in[3];
    float* out = (float*)d_out;

    short* Wp = (short*)d_ws;   // 73728 shorts (144 KB)

    wconv<<<dim3(288), dim3(256), 0, stream>>>(Wq, Wk, Wv, Wp);
    fused_attn<<<dim3(256), dim3(1024), 0, stream>>>(x, Wp, out);
}